// Round 11
// baseline (413.352 us; speedup 1.0000x reference)
//
#include <hip/hip_runtime.h>
#include <math.h>

#define NB 32
#define NS 8192
#define NC 64
#define NM 16
#define NL 4
#define NM2 32                 // 2*M (cos,sin interleaved)
#define TPOS 128               // positions per tile (2 per thread)
#define NT (NS/TPOS)           // 64 tiles per batch
#define PAD 65                 // LDS row pad: banks (p+i)%32 -> 2-way = free,
                               // rows contiguous -> ds_read_b128 vectorizes

typedef float f16v __attribute__((ext_vector_type(16)));
typedef float f8v  __attribute__((ext_vector_type(8)));

static __device__ __forceinline__ f8v zero8() {
    f8v v;
    #pragma unroll
    for (int j = 0; j < 8; ++j) v[j] = 0.0f;
    return v;
}

// A&S 7.1.26 erf (|err|<2e-7) -> exact-form gelu, ~14 VALU ops, no branches.
static __device__ __forceinline__ float gelu_fast(float v) {
    float x  = v * 0.7071067811865475f;
    float ax = fabsf(x);
    float d  = fmaf(0.3275911f, ax, 1.0f);
    float t;
    asm("v_rcp_f32 %0, %1" : "=v"(t) : "v"(d));
    float p = t * fmaf(t, fmaf(t, fmaf(t, fmaf(t, 1.061405429f, -1.453152027f),
                                       1.421413741f), -0.284496736f),
                       0.254829592f);
    float e = __expf(-ax * ax);
    float erfv = fmaf(-p, e, 1.0f);
    erfv = copysignf(erfv, x);
    return 0.5f * v * (1.0f + erfv);
}

// Build trig table T[s][2m]=cos(2*pi*m*s/NS), T[s][2m+1]=sin(2*pi*m*s/NS)
__global__ void k_table(float* __restrict__ T) {
    int s = blockIdx.x * blockDim.x + threadIdx.x;
    if (s >= NS) return;
    const float w = 6.283185307179586f / (float)NS;
    float* row = T + (size_t)s * NM2;
    #pragma unroll
    for (int m = 0; m < NM; ++m) {
        int idx = (m * s) & (NS - 1);
        float a = w * (float)idx;
        float sv, cv;
        sincosf(a, &sv, &cv);
        row[2*m]   = cv;
        row[2*m+1] = sv;
    }
}

// Transpose Wl_w [L][o][i] -> Wt [L][i][o]; d1_w [o][i] -> d1t [i][o]
__global__ void k_prep(const float* __restrict__ Ww, const float* __restrict__ d1w,
                       float* __restrict__ Wt, float* __restrict__ d1t) {
    int idx = blockIdx.x * 256 + threadIdx.x;
    if (idx < NL*NC*NC) {
        int l = idx / (NC*NC), r = idx % (NC*NC);
        int i = r / NC, o = r % NC;
        Wt[idx] = Ww[(size_t)l*NC*NC + (size_t)o*NC + i];
    } else if (idx < NL*NC*NC + NC*NC) {
        int r = idx - NL*NC*NC;
        int i = r / NC, o = r % NC;
        d1t[r] = d1w[(size_t)o*NC + i];
    }
}

// Shared DFT phase: hs pos-major pad-65; lane=c reads hs[ss*PAD+c]
// (contiguous lanes -> conflict-free); T rows wave-uniform s_loads.
static __device__ __forceinline__ void dft_phase(
        const float* __restrict__ hs, const float* __restrict__ T,
        float* __restrict__ partial, int b, int tile, int s0,
        int og, int t) {
    int c = t & 63;
    f8v acc = zero8();
    const float* trow = T + (size_t)s0 * NM2 + og * 8;
    #pragma unroll 4
    for (int ss = 0; ss < TPOS; ++ss) {
        float hv = hs[ss * PAD + c];
        f8v tv = *(const f8v*)(trow + (size_t)ss * NM2);
        acc += hv * tv;
    }
    float* pout = partial + (((size_t)b*NT + tile)*NC + c)*NM2 + og*8;
    *(f8v*)pout = acc;
}

// Encoder fused with layer-0 forward DFT. Block = one 128-position tile.
__global__ void __launch_bounds__(256) k_enc(const float* __restrict__ x,
                                             const float* __restrict__ ew,
                                             const float* __restrict__ eb,
                                             const float* __restrict__ T,
                                             float* __restrict__ h,
                                             float* __restrict__ partial) {
    __shared__ float hs[TPOS * PAD];   // 33.28 KB
    int tile = blockIdx.x, b = blockIdx.y;
    int t = threadIdx.x;
    int og = __builtin_amdgcn_readfirstlane(t >> 6);
    int p  = t & 63;
    int s0 = tile * TPOS;

    float xA = x[(size_t)b*NS + s0 + p];
    float xB = x[(size_t)b*NS + s0 + p + 64];
    f16v ew16 = *(const f16v*)(ew + og*16);
    f16v eb16 = *(const f16v*)(eb + og*16);
    f16v hA = xA * ew16 + eb16;
    f16v hB = xB * ew16 + eb16;

    *(f16v*)(h + ((size_t)b*NS + s0 + p)*NC + og*16)      = hA;
    *(f16v*)(h + ((size_t)b*NS + s0 + p + 64)*NC + og*16) = hB;

    float4* dA = (float4*)&hs[p*PAD + og*16];
    float4* dB = (float4*)&hs[(p+64)*PAD + og*16];
    #pragma unroll
    for (int q = 0; q < 4; ++q) {
        dA[q] = make_float4(hA[4*q], hA[4*q+1], hA[4*q+2], hA[4*q+3]);
        dB[q] = make_float4(hB[4*q], hB[4*q+1], hB[4*q+2], hB[4*q+3]);
    }
    __syncthreads();

    dft_phase(hs, T, partial, b, tile, s0, og, t);
}

// Reduce tile partials -> xf columns (this block's 8 k's), apply complex R
// mixing, pre-scale for inverse. grid (NB, 4).
__global__ void __launch_bounds__(256) k_mix(const float* __restrict__ partial,
                                             const float* __restrict__ Rre,
                                             const float* __restrict__ Rim,
                                             float* __restrict__ yst, int l) {
    __shared__ float xf[NC * 8];   // 2 KB: [c][kk], k = 8*jg + kk
    int b = blockIdx.x, jg = blockIdx.y, t = threadIdx.x;
    #pragma unroll
    for (int e = 0; e < 2; ++e) {
        int idx = t + 256*e;               // 0..511 = c*8 + kk
        int c = idx >> 3, kk = idx & 7;
        const float* pp = partial + (size_t)b*NT*NC*NM2 + (size_t)c*NM2 + 8*jg + kk;
        float s = 0.f;
        #pragma unroll 8
        for (int tile = 0; tile < NT; ++tile)
            s += pp[(size_t)tile * NC * NM2];
        xf[idx] = s;
    }
    __syncthreads();
    {
        int o = t >> 2, mq = t & 3;
        int m = 4*jg + mq;
        float yre = 0.f, yim = 0.f;
        #pragma unroll 8
        for (int i = 0; i < NC; ++i) {
            float xr = xf[i*8 + 2*mq];
            float xs = xf[i*8 + 2*mq + 1];
            size_t ridx = (((size_t)l*NC + i)*NC + o)*NM + m;
            float rr = Rre[ridx], ri = Rim[ridx];
            yre = fmaf(xr, rr, yre); yre = fmaf(xs, ri, yre);
            yim = fmaf(xr, ri, yim); yim = fmaf(-xs, rr, yim);
        }
        float* yb = yst + (size_t)b*NM2*NC;
        if (m == 0) { yb[o] = yre * (1.0f/NS); yb[NC + o] = 0.f; }
        else {
            yb[(size_t)(2*m)*NC + o]   = yre * (2.0f/NS);
            yb[(size_t)(2*m+1)*NC + o] = -yim * (2.0f/NS);
        }
    }
}

// Fused spectral + Wl + GELU (+ next-layer DFT, or decoder when LAST).
template<bool LAST>
__global__ void __launch_bounds__(256) k_spec(float* __restrict__ h,
                                              const float* __restrict__ T,
                                              const float* __restrict__ yst,
                                              const float* __restrict__ Wt,
                                              const float* __restrict__ Wb,
                                              const float* __restrict__ d1t,
                                              const float* __restrict__ d1b,
                                              const float* __restrict__ d2w,
                                              const float* __restrict__ d2b,
                                              float* __restrict__ partial,
                                              float* __restrict__ outp,
                                              int l) {
    __shared__ float hs[TPOS * PAD];   // 33.28 KB
    int tile = blockIdx.x, b = blockIdx.y;
    int t = threadIdx.x;
    int og = __builtin_amdgcn_readfirstlane(t >> 6);
    int p  = t & 63;
    int s0 = tile * TPOS;

    // A: issue coalesced tile loads
    const float4* hblk = (const float4*)(h + ((size_t)b*NS + s0)*NC);
    float4 ld0 = hblk[t];
    float4 ld1 = hblk[t + 256];
    float4 ld2 = hblk[t + 512];
    float4 ld3 = hblk[t + 768];
    float4 ld4 = hblk[t + 1024];
    float4 ld5 = hblk[t + 1280];
    float4 ld6 = hblk[t + 1536];
    float4 ld7 = hblk[t + 1792];

    const float* Wl = Wt + (size_t)l*NC*NC + og*16;    // [i][og*16..)
    const float* bl = Wb + (size_t)l*NC + og*16;
    const float* yb = yst + (size_t)b*NM2*NC + og*16;  // [k][og*16..)

    f16v accA = *(const f16v*)bl;
    f16v accB = accA;

    // B: spectral (overlaps global-load latency); native trig in revolutions;
    // position-B trig = A rotated by the constant 64/NS revolutions.
    {
        f16v y0 = *(const f16v*)yb;        // m=0 cos row (sin row is zero)
        accA += y0;
        accB += y0;
        float rev = (float)(s0 + p) * (1.0f / (float)NS);   // in [0,1)
        float cA1, sA1;
        asm("v_cos_f32 %0, %1" : "=v"(cA1) : "v"(rev));
        asm("v_sin_f32 %0, %1" : "=v"(sA1) : "v"(rev));
        const float cd = 0.99879545620517239f;   // cos(2*pi*64/8192)
        const float sd = 0.04906767432741802f;   // sin(2*pi*64/8192)
        float cB1 = cA1*cd - sA1*sd;
        float sB1 = sA1*cd + cA1*sd;
        float cmA = cA1, smA = sA1, cmB = cB1, smB = sB1;
        #pragma unroll 1
        for (int m = 1; m < NM; ++m) {
            f16v yc  = *(const f16v*)(yb + (size_t)(2*m)*NC);
            f16v ysv = *(const f16v*)(yb + (size_t)(2*m+1)*NC);
            accA += cmA * yc;  accA += smA * ysv;
            accB += cmB * yc;  accB += smB * ysv;
            float cnA = cmA*cA1 - smA*sA1;
            smA = cmA*sA1 + smA*cA1;  cmA = cnA;
            float cnB = cmB*cB1 - smB*sB1;
            smB = cmB*sB1 + smB*cB1;  cmB = cnB;
        }
    }

    // C: stage old h into LDS (padded pos-major rows, b128 stores)
    {
        int ss = t >> 4, q4 = (t & 15) * 4;
        *(float4*)&hs[ss*PAD + q4]       = ld0;
        *(float4*)&hs[(ss+16)*PAD + q4]  = ld1;
        *(float4*)&hs[(ss+32)*PAD + q4]  = ld2;
        *(float4*)&hs[(ss+48)*PAD + q4]  = ld3;
        *(float4*)&hs[(ss+64)*PAD + q4]  = ld4;
        *(float4*)&hs[(ss+80)*PAD + q4]  = ld5;
        *(float4*)&hs[(ss+96)*PAD + q4]  = ld6;
        *(float4*)&hs[(ss+112)*PAD + q4] = ld7;
    }
    __syncthreads();

    // D: dense from LDS rows (b128 reads), W rows shared by both accumulators
    const float* hA = &hs[p * PAD];
    const float* hB = &hs[(p + 64) * PAD];
    #pragma unroll 4
    for (int i4 = 0; i4 < NC; i4 += 4) {
        float4 va = *(const float4*)(hA + i4);
        float4 vb = *(const float4*)(hB + i4);
        f16v w0 = *(const f16v*)(Wl + (size_t)i4*NC);
        f16v w1 = *(const f16v*)(Wl + (size_t)(i4+1)*NC);
        f16v w2 = *(const f16v*)(Wl + (size_t)(i4+2)*NC);
        f16v w3 = *(const f16v*)(Wl + (size_t)(i4+3)*NC);
        accA += va.x * w0;  accB += vb.x * w0;
        accA += va.y * w1;  accB += vb.y * w1;
        accA += va.z * w2;  accB += vb.z * w2;
        accA += va.w * w3;  accB += vb.w * w3;
    }

    // E: gelu (+ global h write unless LAST)
    f16v gA, gB;
    #pragma unroll
    for (int j = 0; j < 16; ++j) gA[j] = gelu_fast(accA[j]);
    #pragma unroll
    for (int j = 0; j < 16; ++j) gB[j] = gelu_fast(accB[j]);
    if (!LAST) {
        *(f16v*)(h + ((size_t)b*NS + s0 + p)*NC + og*16)      = gA;
        *(f16v*)(h + ((size_t)b*NS + s0 + p + 64)*NC + og*16) = gB;
    }

    // F: overwrite LDS with g (all dense reads complete first)
    __syncthreads();
    {
        float4* dA = (float4*)&hs[p*PAD + og*16];
        float4* dB = (float4*)&hs[(p+64)*PAD + og*16];
        #pragma unroll
        for (int q = 0; q < 4; ++q) {
            dA[q] = make_float4(gA[4*q], gA[4*q+1], gA[4*q+2], gA[4*q+3]);
            dB[q] = make_float4(gB[4*q], gB[4*q+1], gB[4*q+2], gB[4*q+3]);
        }
    }
    __syncthreads();

    if (!LAST) {
        // G: forward DFT of the new h tile for the next layer
        dft_phase(hs, T, partial, b, tile, s0, og, t);
    } else {
        // G': decoder from LDS -> out; final reduce reuses hs
        f16v aA = *(const f16v*)(d1b + og*16);
        f16v aB = aA;
        const float* hA2 = &hs[p * PAD];
        const float* hB2 = &hs[(p + 64) * PAD];
        #pragma unroll 4
        for (int i4 = 0; i4 < NC; i4 += 4) {
            float4 va = *(const float4*)(hA2 + i4);
            float4 vb = *(const float4*)(hB2 + i4);
            f16v w0 = *(const f16v*)(d1t + (size_t)i4*NC + og*16);
            f16v w1 = *(const f16v*)(d1t + (size_t)(i4+1)*NC + og*16);
            f16v w2 = *(const f16v*)(d1t + (size_t)(i4+2)*NC + og*16);
            f16v w3 = *(const f16v*)(d1t + (size_t)(i4+3)*NC + og*16);
            aA += va.x * w0;  aB += vb.x * w0;
            aA += va.y * w1;  aB += vb.y * w1;
            aA += va.z * w2;  aB += vb.z * w2;
            aA += va.w * w3;  aB += vb.w * w3;
        }
        float resA = 0.f, resB = 0.f;
        #pragma unroll
        for (int j = 0; j < 16; ++j) {
            float dw = d2w[og*16 + j];
            resA = fmaf(gelu_fast(aA[j]), dw, resA);
            resB = fmaf(gelu_fast(aB[j]), dw, resB);
        }
        __syncthreads();
        hs[og*TPOS + p]      = resA;
        hs[og*TPOS + p + 64] = resB;
        __syncthreads();
        if (t < TPOS) {
            outp[(size_t)b*NS + s0 + t] = d2b[0] + hs[t] + hs[TPOS + t]
                                        + hs[2*TPOS + t] + hs[3*TPOS + t];
        }
    }
}

extern "C" void kernel_launch(void* const* d_in, const int* in_sizes, int n_in,
                              void* d_out, int out_size, void* d_ws, size_t ws_size,
                              hipStream_t stream) {
    const float* input = (const float*)d_in[0];
    const float* enc_w = (const float*)d_in[1];
    const float* enc_b = (const float*)d_in[2];
    const float* R_re  = (const float*)d_in[3];
    const float* R_im  = (const float*)d_in[4];
    const float* Wl_w  = (const float*)d_in[5];
    const float* Wl_b  = (const float*)d_in[6];
    const float* d1_w  = (const float*)d_in[7];
    const float* d1_b  = (const float*)d_in[8];
    const float* d2_w  = (const float*)d_in[9];
    const float* d2_b  = (const float*)d_in[10];
    float* out = (float*)d_out;

    float* ws  = (float*)d_ws;
    float* h   = ws;                               // NB*NS*NC = 16.78M floats
    float* T   = h   + (size_t)NB*NS*NC;           // NS*NM2 = 262144
    float* par = T   + (size_t)NS*NM2;             // NB*NT*NC*NM2 = 4.19M
    float* yst = par + (size_t)NB*NT*NC*NM2;       // NB*NM2*NC = 65536
    float* Wt  = yst + (size_t)NB*NM2*NC;          // NL*NC*NC = 16384
    float* d1t = Wt  + (size_t)NL*NC*NC;           // NC*NC = 4096

    hipLaunchKernelGGL(k_table, dim3(NS/256), dim3(256), 0, stream, T);
    hipLaunchKernelGGL(k_prep, dim3((NL*NC*NC + NC*NC + 255)/256), dim3(256), 0,
                       stream, Wl_w, d1_w, Wt, d1t);
    hipLaunchKernelGGL(k_enc, dim3(NT, NB), dim3(256), 0, stream,
                       input, enc_w, enc_b, T, h, par);
    for (int l = 0; l < NL; ++l) {
        hipLaunchKernelGGL(k_mix, dim3(NB, 4), dim3(256), 0, stream,
                           par, R_re, R_im, yst, l);
        if (l < NL - 1) {
            hipLaunchKernelGGL((k_spec<false>), dim3(NT, NB), dim3(256), 0, stream,
                               h, T, yst, Wt, Wl_b, d1t, d1_b, d2_w, d2_b,
                               par, out, l);
        } else {
            hipLaunchKernelGGL((k_spec<true>), dim3(NT, NB), dim3(256), 0, stream,
                               h, T, yst, Wt, Wl_b, d1t, d1_b, d2_w, d2_b,
                               par, out, l);
        }
    }
}

// Round 12
// 372.746 us; speedup vs baseline: 1.1089x; 1.1089x over previous
//
#include <hip/hip_runtime.h>
#include <math.h>

#define NB 32
#define NS 8192
#define NC 64
#define NM 16
#define NL 4
#define NM2 32                 // 2*M (cos,sin interleaved)
#define TPOS 128               // positions per tile (1 per thread, 512 thr)
#define NT (NS/TPOS)           // 64 tiles per batch
#define PAD 65                 // LDS row pad

typedef float f16v __attribute__((ext_vector_type(16)));
typedef float f4v  __attribute__((ext_vector_type(4)));

static __device__ __forceinline__ f4v zero4() {
    f4v v;
    #pragma unroll
    for (int j = 0; j < 4; ++j) v[j] = 0.0f;
    return v;
}

static __device__ __forceinline__ float gelu_exact(float v) {
    return 0.5f * v * (1.0f + erff(v * 0.7071067811865475f));
}

// Build trig table T[s][2m]=cos(2*pi*m*s/NS), T[s][2m+1]=sin(2*pi*m*s/NS)
__global__ void k_table(float* __restrict__ T) {
    int s = blockIdx.x * blockDim.x + threadIdx.x;
    if (s >= NS) return;
    const float w = 6.283185307179586f / (float)NS;
    float* row = T + (size_t)s * NM2;
    #pragma unroll
    for (int m = 0; m < NM; ++m) {
        int idx = (m * s) & (NS - 1);
        float a = w * (float)idx;
        float sv, cv;
        sincosf(a, &sv, &cv);
        row[2*m]   = cv;
        row[2*m+1] = sv;
    }
}

// Transpose Wl_w [L][o][i] -> Wt [L][i][o]; d1_w [o][i] -> d1t [i][o]
__global__ void k_prep(const float* __restrict__ Ww, const float* __restrict__ d1w,
                       float* __restrict__ Wt, float* __restrict__ d1t) {
    int idx = blockIdx.x * 256 + threadIdx.x;
    if (idx < NL*NC*NC) {
        int l = idx / (NC*NC), r = idx % (NC*NC);
        int i = r / NC, o = r % NC;
        Wt[idx] = Ww[(size_t)l*NC*NC + (size_t)o*NC + i];
    } else if (idx < NL*NC*NC + NC*NC) {
        int r = idx - NL*NC*NC;
        int i = r / NC, o = r % NC;
        d1t[r] = d1w[(size_t)o*NC + i];
    }
}

// Shared DFT phase (512 threads): lane c = t&63, wave-group kg = t>>6 owns
// 4 modes. hs pos-major pad-65: lanes read hs[ss*PAD+c] contiguous ->
// conflict-free; T rows wave-uniform s_loads.
static __device__ __forceinline__ void dft_phase(
        const float* __restrict__ hs, const float* __restrict__ T,
        float* __restrict__ partial, int b, int tile, int s0, int t) {
    int c  = t & 63;
    int kg = __builtin_amdgcn_readfirstlane(t >> 6);   // 0..7
    f4v acc = zero4();
    const float* trow = T + (size_t)s0 * NM2 + kg * 4;
    #pragma unroll 4
    for (int ss = 0; ss < TPOS; ++ss) {
        float hv = hs[ss * PAD + c];
        f4v tv = *(const f4v*)(trow + (size_t)ss * NM2);
        acc += hv * tv;
    }
    float* pout = partial + (((size_t)b*NT + tile)*NC + c)*NM2 + kg*4;
    *(f4v*)pout = acc;
}

// Encoder fused with layer-0 forward DFT. Block = one 128-position tile,
// 512 threads: og = t>>7 (channel group), p = t&127 (position).
__global__ void __launch_bounds__(512) k_enc(const float* __restrict__ x,
                                             const float* __restrict__ ew,
                                             const float* __restrict__ eb,
                                             const float* __restrict__ T,
                                             float* __restrict__ h,
                                             float* __restrict__ partial) {
    __shared__ float hs[TPOS * PAD];   // 33.28 KB
    int tile = blockIdx.x, b = blockIdx.y;
    int t = threadIdx.x;
    int og = __builtin_amdgcn_readfirstlane(t >> 7);
    int p  = t & 127;
    int s0 = tile * TPOS;

    float xv = x[(size_t)b*NS + s0 + p];
    f16v ew16 = *(const f16v*)(ew + og*16);
    f16v eb16 = *(const f16v*)(eb + og*16);
    f16v hv = xv * ew16 + eb16;

    *(f16v*)(h + ((size_t)b*NS + s0 + p)*NC + og*16) = hv;

    #pragma unroll
    for (int j = 0; j < 16; ++j) hs[p*PAD + og*16 + j] = hv[j];
    __syncthreads();

    dft_phase(hs, T, partial, b, tile, s0, t);
}

// Reduce tile partials -> xf columns (this block's 8 k's), apply complex R
// mixing, pre-scale for inverse. grid (NB, 4).
__global__ void __launch_bounds__(256) k_mix(const float* __restrict__ partial,
                                             const float* __restrict__ Rre,
                                             const float* __restrict__ Rim,
                                             float* __restrict__ yst, int l) {
    __shared__ float xf[NC * 8];   // 2 KB: [c][kk], k = 8*jg + kk
    int b = blockIdx.x, jg = blockIdx.y, t = threadIdx.x;
    #pragma unroll
    for (int e = 0; e < 2; ++e) {
        int idx = t + 256*e;               // 0..511 = c*8 + kk
        int c = idx >> 3, kk = idx & 7;
        const float* pp = partial + (size_t)b*NT*NC*NM2 + (size_t)c*NM2 + 8*jg + kk;
        float s = 0.f;
        #pragma unroll 8
        for (int tile = 0; tile < NT; ++tile)
            s += pp[(size_t)tile * NC * NM2];
        xf[idx] = s;
    }
    __syncthreads();
    {
        int o = t >> 2, mq = t & 3;
        int m = 4*jg + mq;
        float yre = 0.f, yim = 0.f;
        #pragma unroll 8
        for (int i = 0; i < NC; ++i) {
            float xr = xf[i*8 + 2*mq];
            float xs = xf[i*8 + 2*mq + 1];
            size_t ridx = (((size_t)l*NC + i)*NC + o)*NM + m;
            float rr = Rre[ridx], ri = Rim[ridx];
            yre = fmaf(xr, rr, yre); yre = fmaf(xs, ri, yre);
            yim = fmaf(xr, ri, yim); yim = fmaf(-xs, rr, yim);
        }
        float* yb = yst + (size_t)b*NM2*NC;
        if (m == 0) { yb[o] = yre * (1.0f/NS); yb[NC + o] = 0.f; }
        else {
            yb[(size_t)(2*m)*NC + o]   = yre * (2.0f/NS);
            yb[(size_t)(2*m+1)*NC + o] = -yim * (2.0f/NS);
        }
    }
}

// Fused spectral + Wl + GELU (+ next-layer DFT, or decoder when LAST).
// 512 threads, 1 position each: og = t>>7, p = t&127. Phases identical to
// the proven R9 structure (scalar LDS staging, scalar dense reads).
template<bool LAST>
__global__ void __launch_bounds__(512) k_spec(float* __restrict__ h,
                                              const float* __restrict__ T,
                                              const float* __restrict__ yst,
                                              const float* __restrict__ Wt,
                                              const float* __restrict__ Wb,
                                              const float* __restrict__ d1t,
                                              const float* __restrict__ d1b,
                                              const float* __restrict__ d2w,
                                              const float* __restrict__ d2b,
                                              float* __restrict__ partial,
                                              float* __restrict__ outp,
                                              int l) {
    __shared__ float hs[TPOS * PAD];   // 33.28 KB
    int tile = blockIdx.x, b = blockIdx.y;
    int t = threadIdx.x;
    int og = __builtin_amdgcn_readfirstlane(t >> 7);
    int p  = t & 127;
    int s0 = tile * TPOS;

    // A: issue coalesced tile loads (128*64 floats / 512 thr = 4 float4)
    const float4* hblk = (const float4*)(h + ((size_t)b*NS + s0)*NC);
    float4 ld0 = hblk[t];
    float4 ld1 = hblk[t + 512];
    float4 ld2 = hblk[t + 1024];
    float4 ld3 = hblk[t + 1536];

    const float* Wl = Wt + (size_t)l*NC*NC + og*16;    // [i][og*16..)
    const float* bl = Wb + (size_t)l*NC + og*16;
    const float* yb = yst + (size_t)b*NM2*NC + og*16;  // [k][og*16..)

    f16v acc = *(const f16v*)bl;

    // B: spectral (overlaps global-load latency)
    {
        acc += *(const f16v*)yb;           // m=0 cos row (sin row is zero)
        float ang = (float)(s0 + p) * (6.283185307179586f / (float)NS);
        float c1, s1;
        sincosf(ang, &s1, &c1);
        float cm = c1, sm = s1;
        #pragma unroll 1
        for (int m = 1; m < NM; ++m) {
            f16v yc  = *(const f16v*)(yb + (size_t)(2*m)*NC);
            f16v ysv = *(const f16v*)(yb + (size_t)(2*m+1)*NC);
            acc += cm * yc;
            acc += sm * ysv;
            float cn = cm*c1 - sm*s1;
            sm = cm*s1 + sm*c1;
            cm = cn;
        }
    }

    // C: stage old h into LDS (scalar stores, padded pos-major rows)
    {
        int ss = t >> 4, q4 = (t & 15) * 4;
        float* d;
        d = &hs[ss*PAD + q4];       d[0]=ld0.x; d[1]=ld0.y; d[2]=ld0.z; d[3]=ld0.w;
        d = &hs[(ss+32)*PAD + q4];  d[0]=ld1.x; d[1]=ld1.y; d[2]=ld1.z; d[3]=ld1.w;
        d = &hs[(ss+64)*PAD + q4];  d[0]=ld2.x; d[1]=ld2.y; d[2]=ld2.z; d[3]=ld2.w;
        d = &hs[(ss+96)*PAD + q4];  d[0]=ld3.x; d[1]=ld3.y; d[2]=ld3.z; d[3]=ld3.w;
    }
    __syncthreads();

    // D: dense from LDS (scalar reads), W rows wave-uniform s_loads
    const float* hrow = &hs[p * PAD];
    #pragma unroll 8
    for (int i = 0; i < NC; ++i) {
        float hv = hrow[i];
        f16v w = *(const f16v*)(Wl + (size_t)i*NC);
        acc += hv * w;
    }

    // E: gelu (+ global h write unless LAST)
    f16v g;
    #pragma unroll
    for (int j = 0; j < 16; ++j) g[j] = gelu_exact(acc[j]);
    if (!LAST) {
        *(f16v*)(h + ((size_t)b*NS + s0 + p)*NC + og*16) = g;
    }

    // F: overwrite LDS with g (all dense reads complete first)
    __syncthreads();
    #pragma unroll
    for (int j = 0; j < 16; ++j) hs[p*PAD + og*16 + j] = g[j];
    __syncthreads();

    if (!LAST) {
        // G: forward DFT of the new h tile for the next layer
        dft_phase(hs, T, partial, b, tile, s0, t);
    } else {
        // G': decoder from LDS -> out; final reduce reuses hs
        f16v a = *(const f16v*)(d1b + og*16);
        const float* hr = &hs[p * PAD];
        #pragma unroll 8
        for (int i = 0; i < NC; ++i) {
            float hv = hr[i];
            f16v w = *(const f16v*)(d1t + (size_t)i*NC + og*16);
            a += hv * w;
        }
        float res = 0.f;
        #pragma unroll
        for (int j = 0; j < 16; ++j)
            res = fmaf(gelu_exact(a[j]), d2w[og*16 + j], res);
        __syncthreads();
        hs[og*TPOS + p] = res;
        __syncthreads();
        if (t < TPOS) {
            outp[(size_t)b*NS + s0 + t] = d2b[0] + hs[t] + hs[TPOS + t]
                                        + hs[2*TPOS + t] + hs[3*TPOS + t];
        }
    }
}

extern "C" void kernel_launch(void* const* d_in, const int* in_sizes, int n_in,
                              void* d_out, int out_size, void* d_ws, size_t ws_size,
                              hipStream_t stream) {
    const float* input = (const float*)d_in[0];
    const float* enc_w = (const float*)d_in[1];
    const float* enc_b = (const float*)d_in[2];
    const float* R_re  = (const float*)d_in[3];
    const float* R_im  = (const float*)d_in[4];
    const float* Wl_w  = (const float*)d_in[5];
    const float* Wl_b  = (const float*)d_in[6];
    const float* d1_w  = (const float*)d_in[7];
    const float* d1_b  = (const float*)d_in[8];
    const float* d2_w  = (const float*)d_in[9];
    const float* d2_b  = (const float*)d_in[10];
    float* out = (float*)d_out;

    float* ws  = (float*)d_ws;
    float* h   = ws;                               // NB*NS*NC = 16.78M floats
    float* T   = h   + (size_t)NB*NS*NC;           // NS*NM2 = 262144
    float* par = T   + (size_t)NS*NM2;             // NB*NT*NC*NM2 = 4.19M
    float* yst = par + (size_t)NB*NT*NC*NM2;       // NB*NM2*NC = 65536
    float* Wt  = yst + (size_t)NB*NM2*NC;          // NL*NC*NC = 16384
    float* d1t = Wt  + (size_t)NL*NC*NC;           // NC*NC = 4096

    hipLaunchKernelGGL(k_table, dim3(NS/256), dim3(256), 0, stream, T);
    hipLaunchKernelGGL(k_prep, dim3((NL*NC*NC + NC*NC + 255)/256), dim3(256), 0,
                       stream, Wl_w, d1_w, Wt, d1t);
    hipLaunchKernelGGL(k_enc, dim3(NT, NB), dim3(512), 0, stream,
                       input, enc_w, enc_b, T, h, par);
    for (int l = 0; l < NL; ++l) {
        hipLaunchKernelGGL(k_mix, dim3(NB, 4), dim3(256), 0, stream,
                           par, R_re, R_im, yst, l);
        if (l < NL - 1) {
            hipLaunchKernelGGL((k_spec<false>), dim3(NT, NB), dim3(512), 0, stream,
                               h, T, yst, Wt, Wl_b, d1t, d1_b, d2_w, d2_b,
                               par, out, l);
        } else {
            hipLaunchKernelGGL((k_spec<true>), dim3(NT, NB), dim3(512), 0, stream,
                               h, T, yst, Wt, Wl_b, d1t, d1_b, d2_w, d2_b,
                               par, out, l);
        }
    }
}

// Round 13
// 360.671 us; speedup vs baseline: 1.1461x; 1.0335x over previous
//
#include <hip/hip_runtime.h>
#include <math.h>

#define NB 32
#define NS 8192
#define NC 64
#define NM 16
#define NL 4
#define NM2 32                 // 2*M (cos,sin interleaved)
#define TPOS 128               // positions per tile
#define NT (NS/TPOS)           // 64 tiles per batch
#define PAD 65                 // fp32 LDS row pad (k_enc / LAST decoder)
#define APAD 68                // bf16 h-tile row stride (pad 4: 2-way banks, 8B align)
#define GPAD 132               // bf16 gT row stride (pad 4: 2-way banks, 8B align)

typedef float f16v  __attribute__((ext_vector_type(16)));
typedef float f4v   __attribute__((ext_vector_type(4)));
typedef short bf16x8 __attribute__((ext_vector_type(8)));
typedef short bf16x4 __attribute__((ext_vector_type(4)));

#define MFMA16(a,b,c) __builtin_amdgcn_mfma_f32_16x16x32_bf16(a,b,c,0,0,0)

static __device__ __forceinline__ unsigned short f2bf(float x) {
    unsigned u = __float_as_uint(x);
    u += 0x7FFFu + ((u >> 16) & 1u);          // round-to-nearest-even
    return (unsigned short)(u >> 16);
}
static __device__ __forceinline__ float bf2f(unsigned short b) {
    return __uint_as_float(((unsigned)b) << 16);
}
static __device__ __forceinline__ bf16x8 ld8l(const unsigned short* p) {
    bf16x4 a = *(const bf16x4*)p;
    bf16x4 b = *(const bf16x4*)(p + 4);
    return __builtin_shufflevector(a, b, 0, 1, 2, 3, 4, 5, 6, 7);
}
static __device__ __forceinline__ float gelu_exact(float v) {
    return 0.5f * v * (1.0f + erff(v * 0.7071067811865475f));
}

// Trig tables: T fp32 [s][32]; Thi/Tlo bf16 [s][32] (spectral A-frags);
// TThi/TTlo bf16 [32][s] (DFT B-frags).
__global__ void k_table(float* __restrict__ T,
                        unsigned short* __restrict__ Thi,
                        unsigned short* __restrict__ Tlo,
                        unsigned short* __restrict__ TThi,
                        unsigned short* __restrict__ TTlo) {
    int s = blockIdx.x * 256 + threadIdx.x;
    if (s >= NS) return;
    const float w = 6.283185307179586f / (float)NS;
    #pragma unroll
    for (int m = 0; m < NM; ++m) {
        int idx = (m * s) & (NS - 1);
        float sv, cv;
        sincosf(w * (float)idx, &sv, &cv);
        T[(size_t)s*NM2 + 2*m]   = cv;
        T[(size_t)s*NM2 + 2*m+1] = sv;
        unsigned short ch = f2bf(cv), cl = f2bf(cv - bf2f(f2bf(cv)));
        unsigned short sh = f2bf(sv), sl = f2bf(sv - bf2f(f2bf(sv)));
        Thi[(size_t)s*NM2 + 2*m]   = ch;  Tlo[(size_t)s*NM2 + 2*m]   = cl;
        Thi[(size_t)s*NM2 + 2*m+1] = sh;  Tlo[(size_t)s*NM2 + 2*m+1] = sl;
        TThi[(size_t)(2*m)*NS + s]   = ch;  TTlo[(size_t)(2*m)*NS + s]   = cl;
        TThi[(size_t)(2*m+1)*NS + s] = sh;  TTlo[(size_t)(2*m+1)*NS + s] = sl;
    }
}

// Wb: bf16 hi/lo split of Wl_w [l][o][i] (B-frag layout, i contiguous);
// d1t: fp32 transpose of d1_w (LAST VALU decoder).
__global__ void k_prep(const float* __restrict__ Ww, const float* __restrict__ d1w,
                       unsigned short* __restrict__ Wbhi,
                       unsigned short* __restrict__ Wblo,
                       float* __restrict__ d1t) {
    int idx = blockIdx.x * 256 + threadIdx.x;
    if (idx < NL*NC*NC) {
        float v = Ww[idx];
        unsigned short hi = f2bf(v);
        Wbhi[idx] = hi;
        Wblo[idx] = f2bf(v - bf2f(hi));
    } else if (idx < NL*NC*NC + NC*NC) {
        int r = idx - NL*NC*NC;
        int i = r / NC, o = r % NC;
        d1t[r] = d1w[(size_t)o*NC + i];
    }
}

// fp32 DFT phase for k_enc (proven R12 code).
static __device__ __forceinline__ void dft_phase(
        const float* __restrict__ hs, const float* __restrict__ T,
        float* __restrict__ partial, int b, int tile, int s0, int t) {
    int c  = t & 63;
    int kg = __builtin_amdgcn_readfirstlane(t >> 6);   // 0..7
    f4v acc = {0.f, 0.f, 0.f, 0.f};
    const float* trow = T + (size_t)s0 * NM2 + kg * 4;
    #pragma unroll 4
    for (int ss = 0; ss < TPOS; ++ss) {
        float hv = hs[ss * PAD + c];
        f4v tv = *(const f4v*)(trow + (size_t)ss * NM2);
        acc += hv * tv;
    }
    float* pout = partial + (((size_t)b*NT + tile)*NC + c)*NM2 + kg*4;
    *(f4v*)pout = acc;
}

// Encoder fused with layer-0 forward DFT (R12, unchanged).
__global__ void __launch_bounds__(512) k_enc(const float* __restrict__ x,
                                             const float* __restrict__ ew,
                                             const float* __restrict__ eb,
                                             const float* __restrict__ T,
                                             float* __restrict__ h,
                                             float* __restrict__ partial) {
    __shared__ float hs[TPOS * PAD];
    int tile = blockIdx.x, b = blockIdx.y;
    int t = threadIdx.x;
    int og = __builtin_amdgcn_readfirstlane(t >> 7);
    int p  = t & 127;
    int s0 = tile * TPOS;

    float xv = x[(size_t)b*NS + s0 + p];
    f16v ew16 = *(const f16v*)(ew + og*16);
    f16v eb16 = *(const f16v*)(eb + og*16);
    f16v hv = xv * ew16 + eb16;

    *(f16v*)(h + ((size_t)b*NS + s0 + p)*NC + og*16) = hv;

    #pragma unroll
    for (int j = 0; j < 16; ++j) hs[p*PAD + og*16 + j] = hv[j];
    __syncthreads();

    dft_phase(hs, T, partial, b, tile, s0, t);
}

// Reduce tile partials, complex-mix with R, pre-scale, output TRANSPOSED
// bf16 hi/lo ysbT[b][o][k] (spectral B-frags). grid (NB, 4).
__global__ void __launch_bounds__(256) k_mix(const float* __restrict__ partial,
                                             const float* __restrict__ Rre,
                                             const float* __restrict__ Rim,
                                             unsigned short* __restrict__ ysbThi,
                                             unsigned short* __restrict__ ysbTlo,
                                             int l) {
    __shared__ float xf[NC * 8];
    int b = blockIdx.x, jg = blockIdx.y, t = threadIdx.x;
    #pragma unroll
    for (int e = 0; e < 2; ++e) {
        int idx = t + 256*e;               // c*8 + kk
        int c = idx >> 3, kk = idx & 7;
        const float* pp = partial + (size_t)b*NT*NC*NM2 + (size_t)c*NM2 + 8*jg + kk;
        float s = 0.f;
        #pragma unroll 8
        for (int tile = 0; tile < NT; ++tile)
            s += pp[(size_t)tile * NC * NM2];
        xf[idx] = s;
    }
    __syncthreads();
    {
        int o = t >> 2, mq = t & 3;
        int m = 4*jg + mq;
        float yre = 0.f, yim = 0.f;
        #pragma unroll 8
        for (int i = 0; i < NC; ++i) {
            float xr = xf[i*8 + 2*mq];
            float xs = xf[i*8 + 2*mq + 1];
            size_t ridx = (((size_t)l*NC + i)*NC + o)*NM + m;
            float rr = Rre[ridx], ri = Rim[ridx];
            yre = fmaf(xr, rr, yre); yre = fmaf(xs, ri, yre);
            yim = fmaf(xr, ri, yim); yim = fmaf(-xs, rr, yim);
        }
        float v0, v1;
        if (m == 0) { v0 = yre * (1.0f/NS); v1 = 0.f; }
        else        { v0 = yre * (2.0f/NS); v1 = -yim * (2.0f/NS); }
        size_t yb = ((size_t)b*NC + o)*NM2;
        unsigned short h0 = f2bf(v0);
        ysbThi[yb + 2*m]   = h0;  ysbTlo[yb + 2*m]   = f2bf(v0 - bf2f(h0));
        unsigned short h1 = f2bf(v1);
        ysbThi[yb + 2*m+1] = h1;  ysbTlo[yb + 2*m+1] = f2bf(v1 - bf2f(h1));
    }
}

// Fused spectral + dense + GELU via split-bf16 MFMA; then next-layer DFT
// via MFMA (!LAST) or VALU decoder (LAST). 512 thr; wave w = M-block w.
template<bool LAST>
__global__ void __launch_bounds__(512) k_spec(float* __restrict__ h,
                                              const unsigned short* __restrict__ Thi,
                                              const unsigned short* __restrict__ Tlo,
                                              const unsigned short* __restrict__ TThi,
                                              const unsigned short* __restrict__ TTlo,
                                              const unsigned short* __restrict__ ysbThi,
                                              const unsigned short* __restrict__ ysbTlo,
                                              const unsigned short* __restrict__ Wbhi,
                                              const unsigned short* __restrict__ Wblo,
                                              const float* __restrict__ Wlb,
                                              const float* __restrict__ d1t,
                                              const float* __restrict__ d1b,
                                              const float* __restrict__ d2w,
                                              const float* __restrict__ d2b,
                                              float* __restrict__ partial,
                                              float* __restrict__ outp,
                                              int l) {
    __shared__ __align__(16) unsigned short uLDS[2 * TPOS * APAD];  // 34816 B
    unsigned short* hsAhi = uLDS;
    unsigned short* hsAlo = uLDS + TPOS * APAD;

    int tile = blockIdx.x, b = blockIdx.y;
    int t = threadIdx.x;
    int lane = t & 63, w = t >> 6;          // w = M-block (wave) index 0..7
    int lm = lane & 15, g = lane >> 4;      // fragment coords
    int s0 = tile * TPOS;

    // --- stage previous-layer h -> bf16 hi/lo LDS tile [pos][APAD] ---
    const float4* hblk = (const float4*)(h + ((size_t)b*NS + s0)*NC);
    #pragma unroll
    for (int j = 0; j < 4; ++j) {
        float4 v = hblk[t + 512*j];
        int idx = t + 512*j;
        int pos = idx >> 4, q4 = (idx & 15) * 4;
        float vv[4] = {v.x, v.y, v.z, v.w};
        bf16x4 hi4, lo4;
        #pragma unroll
        for (int e = 0; e < 4; ++e) {
            unsigned short hh = f2bf(vv[e]);
            hi4[e] = (short)hh;
            lo4[e] = (short)f2bf(vv[e] - bf2f(hh));
        }
        *(bf16x4*)(&hsAhi[pos*APAD + q4]) = hi4;
        *(bf16x4*)(&hsAlo[pos*APAD + q4]) = lo4;
    }
    __syncthreads();

    // --- A-frags ---
    bf16x8 aHi[2], aLo[2];
    #pragma unroll
    for (int k2 = 0; k2 < 2; ++k2) {
        int eo = (w*16 + lm)*APAD + k2*32 + 8*g;
        aHi[k2] = ld8l(&hsAhi[eo]);
        aLo[k2] = ld8l(&hsAlo[eo]);
    }
    bf16x8 tHi = *(const bf16x8*)(Thi + (size_t)(s0 + w*16 + lm)*NM2 + 8*g);
    bf16x8 tLo = *(const bf16x8*)(Tlo + (size_t)(s0 + w*16 + lm)*NM2 + 8*g);

    // --- accumulators: bias broadcast along rows ---
    f4v acc[4];
    #pragma unroll
    for (int N = 0; N < 4; ++N) {
        float bv = Wlb[(size_t)l*NC + N*16 + lm];
        acc[N] = (f4v){bv, bv, bv, bv};
    }

    // --- spectral GEMM: T(128x32) @ ysT(32x64) ---
    #pragma unroll
    for (int N = 0; N < 4; ++N) {
        size_t yo = ((size_t)b*NC + N*16 + lm)*NM2 + 8*g;
        bf16x8 yHi = *(const bf16x8*)(ysbThi + yo);
        bf16x8 yLo = *(const bf16x8*)(ysbTlo + yo);
        acc[N] = MFMA16(tHi, yHi, acc[N]);
        acc[N] = MFMA16(tHi, yLo, acc[N]);
        acc[N] = MFMA16(tLo, yHi, acc[N]);
    }

    // --- dense GEMM: h(128x64) @ W^T(64x64), chained into acc ---
    #pragma unroll
    for (int k2 = 0; k2 < 2; ++k2) {
        #pragma unroll
        for (int N = 0; N < 4; ++N) {
            size_t wo = ((size_t)l*NC + N*16 + lm)*NC + k2*32 + 8*g;
            bf16x8 wHi = *(const bf16x8*)(Wbhi + wo);
            bf16x8 wLo = *(const bf16x8*)(Wblo + wo);
            acc[N] = MFMA16(aHi[k2], wHi, acc[N]);
            acc[N] = MFMA16(aHi[k2], wLo, acc[N]);
            acc[N] = MFMA16(aLo[k2], wHi, acc[N]);
        }
    }

    // --- GELU epilogue (D layout: pos = w*16 + g*4 + r, o = N*16 + lm) ---
    f4v gv[4];
    #pragma unroll
    for (int N = 0; N < 4; ++N)
        #pragma unroll
        for (int r = 0; r < 4; ++r)
            gv[N][r] = gelu_exact(acc[N][r]);

    if (!LAST) {
        #pragma unroll
        for (int N = 0; N < 4; ++N)
            #pragma unroll
            for (int r = 0; r < 4; ++r)
                h[((size_t)b*NS + s0 + w*16 + g*4 + r)*NC + N*16 + lm] = gv[N][r];
    }

    __syncthreads();   // all hsA reads done -> safe to overlay

    if (!LAST) {
        // --- write gT bf16 hi/lo [c][GPAD] (overlay on uLDS) ---
        unsigned short* gThi = uLDS;
        unsigned short* gTlo = uLDS + NC * GPAD;
        #pragma unroll
        for (int N = 0; N < 4; ++N) {
            int c = N*16 + lm;
            #pragma unroll
            for (int r = 0; r < 4; ++r) {
                int pos = w*16 + g*4 + r;
                float v = gv[N][r];
                unsigned short hh = f2bf(v);
                gThi[c*GPAD + pos] = hh;
                gTlo[c*GPAD + pos] = f2bf(v - bf2f(hh));
            }
        }
        __syncthreads();

        // --- DFT GEMM: gT(64x128) @ T(128x32); wave -> (Mblk, Nblk) tile ---
        int Mblk = w & 3, Nblk = w >> 2;
        f4v pacc = {0.f, 0.f, 0.f, 0.f};
        #pragma unroll
        for (int ks = 0; ks < 4; ++ks) {
            int eo = (Mblk*16 + lm)*GPAD + ks*32 + 8*g;
            bf16x8 gHi = ld8l(&gThi[eo]);
            bf16x8 gLo = ld8l(&gTlo[eo]);
            size_t to = (size_t)(Nblk*16 + lm)*NS + s0 + ks*32 + 8*g;
            bf16x8 tbHi = *(const bf16x8*)(TThi + to);
            bf16x8 tbLo = *(const bf16x8*)(TTlo + to);
            pacc = MFMA16(gHi, tbHi, pacc);
            pacc = MFMA16(gHi, tbLo, pacc);
            pacc = MFMA16(gLo, tbHi, pacc);
        }
        float* pout = partial + ((size_t)b*NT + tile)*NC*NM2;
        #pragma unroll
        for (int r = 0; r < 4; ++r) {
            int c = Mblk*16 + g*4 + r;
            pout[(size_t)c*NM2 + Nblk*16 + lm] = pacc[r];
        }
    } else {
        // --- write g fp32 [pos][PAD], then VALU decoder (proven R12 G') ---
        float* hsf = (float*)uLDS;   // 8320 floats <= 8704 available
        #pragma unroll
        for (int N = 0; N < 4; ++N)
            #pragma unroll
            for (int r = 0; r < 4; ++r)
                hsf[(w*16 + g*4 + r)*PAD + N*16 + lm] = gv[N][r];
        __syncthreads();

        int og2 = __builtin_amdgcn_readfirstlane(t >> 7);
        int p2  = t & 127;
        f16v a = *(const f16v*)(d1b + og2*16);
        const float* hr = hsf + p2*PAD;
        #pragma unroll 8
        for (int i = 0; i < NC; ++i) {
            float hv = hr[i];
            f16v wv = *(const f16v*)(d1t + (size_t)i*NC + og2*16);
            a += hv * wv;
        }
        float res = 0.f;
        #pragma unroll
        for (int j = 0; j < 16; ++j)
            res = fmaf(gelu_exact(a[j]), d2w[og2*16 + j], res);
        __syncthreads();
        hsf[og2*TPOS + p2] = res;
        __syncthreads();
        if (t < TPOS) {
            outp[(size_t)b*NS + s0 + t] = d2b[0] + hsf[t] + hsf[TPOS + t]
                                        + hsf[2*TPOS + t] + hsf[3*TPOS + t];
        }
    }
}

extern "C" void kernel_launch(void* const* d_in, const int* in_sizes, int n_in,
                              void* d_out, int out_size, void* d_ws, size_t ws_size,
                              hipStream_t stream) {
    const float* input = (const float*)d_in[0];
    const float* enc_w = (const float*)d_in[1];
    const float* enc_b = (const float*)d_in[2];
    const float* R_re  = (const float*)d_in[3];
    const float* R_im  = (const float*)d_in[4];
    const float* Wl_w  = (const float*)d_in[5];
    const float* Wl_b  = (const float*)d_in[6];
    const float* d1_w  = (const float*)d_in[7];
    const float* d1_b  = (const float*)d_in[8];
    const float* d2_w  = (const float*)d_in[9];
    const float* d2_b  = (const float*)d_in[10];
    float* out = (float*)d_out;

    float* ws  = (float*)d_ws;
    float* h   = ws;                               // 16,777,216 f
    float* T   = h   + (size_t)NB*NS*NC;           // 262,144 f
    float* par = T   + (size_t)NS*NM2;             // 4,194,304 f
    float* d1t = par + (size_t)NB*NT*NC*NM2;       // 4,096 f
    unsigned short* Thi    = (unsigned short*)(d1t + NC*NC);
    unsigned short* Tlo    = Thi    + (size_t)NS*NM2;
    unsigned short* TThi   = Tlo    + (size_t)NS*NM2;
    unsigned short* TTlo   = TThi   + (size_t)NM2*NS;
    unsigned short* ysbThi = TTlo   + (size_t)NM2*NS;
    unsigned short* ysbTlo = ysbThi + (size_t)NB*NC*NM2;
    unsigned short* Wbhi   = ysbTlo + (size_t)NB*NC*NM2;
    unsigned short* Wblo   = Wbhi   + (size_t)NL*NC*NC;

    hipLaunchKernelGGL(k_table, dim3(NS/256), dim3(256), 0, stream,
                       T, Thi, Tlo, TThi, TTlo);
    hipLaunchKernelGGL(k_prep, dim3((NL*NC*NC + NC*NC + 255)/256), dim3(256), 0,
                       stream, Wl_w, d1_w, Wbhi, Wblo, d1t);
    hipLaunchKernelGGL(k_enc, dim3(NT, NB), dim3(512), 0, stream,
                       input, enc_w, enc_b, T, h, par);
    for (int l = 0; l < NL; ++l) {
        hipLaunchKernelGGL(k_mix, dim3(NB, 4), dim3(256), 0, stream,
                           par, R_re, R_im, ysbThi, ysbTlo, l);
        if (l < NL - 1) {
            hipLaunchKernelGGL((k_spec<false>), dim3(NT, NB), dim3(512), 0, stream,
                               h, Thi, Tlo, TThi, TTlo, ysbThi, ysbTlo,
                               Wbhi, Wblo, Wl_b, d1t, d1_b, d2_w, d2_b,
                               par, out, l);
        } else {
            hipLaunchKernelGGL((k_spec<true>), dim3(NT, NB), dim3(512), 0, stream,
                               h, Thi, Tlo, TThi, TTlo, ysbThi, ysbTlo,
                               Wbhi, Wblo, Wl_b, d1t, d1_b, d2_w, d2_b,
                               par, out, l);
        }
    }
}